// Round 4
// baseline (186.393 us; speedup 1.0000x reference)
//
#include <hip/hip_runtime.h>
#include <math.h>

// Problem constants (from reference: B,C,H,W = 16,64,256,256; RATIO=2, GROUPS=4)
#define BATCH 16
#define CIN   64
#define HIN   256
#define WIN   256
#define HOUT  128
#define WOUT  128
#define NPIX  (HIN * WIN)          // 65536
#define OUT0_SIZE ((size_t)BATCH * CIN * HOUT * WOUT)   // 16777216

// -------------------------------------------------------------------------
// Kernel 1: fused conv1x1(w_off) , sigmoid(conv1x1(w_sc)) * 0.5 * off,
// pixel_unshuffle + rearrange -> offg[bg, hh, ww, two]
// Closed form: offg[b, grp, hh, ww, two] = off_conv[b, grp>>1, 2hh+(grp&1), 2ww+two]
// Thread handles 4 consecutive pixels (same input row) -> float4 loads/stores.
// -------------------------------------------------------------------------
__global__ __launch_bounds__(256) void k_offsets(
    const float* __restrict__ x,
    const float* __restrict__ w_off, const float* __restrict__ b_off,
    const float* __restrict__ w_sc,  const float* __restrict__ b_sc,
    float* __restrict__ offg)
{
    __shared__ float sw[256];   // [0:64)=w_off ch0, [64:128)=w_off ch1,
                                // [128:192)=w_sc ch0, [192:256)=w_sc ch1
    int t = threadIdx.x;
    sw[t] = (t < 128) ? w_off[t] : w_sc[t - 128];
    __syncthreads();

    float bo0 = b_off[0], bo1 = b_off[1];
    float bs0 = b_sc[0],  bs1 = b_sc[1];

    int gid = blockIdx.x * 256 + t;     // total = BATCH * NPIX/4 = 262144
    int b   = gid >> 14;                // NPIX/4 = 16384 quads per batch
    int p4  = (gid & 16383) << 2;       // first of 4 consecutive pixels (same row)

    const float* xb = x + (size_t)b * CIN * NPIX + p4;

    float a0[4] = {0,0,0,0}, a1[4] = {0,0,0,0};  // off dot, ch0/ch1
    float s0[4] = {0,0,0,0}, s1[4] = {0,0,0,0};  // scale dot, ch0/ch1

    #pragma unroll 8
    for (int c = 0; c < CIN; ++c) {
        float4 xv = *reinterpret_cast<const float4*>(xb + (size_t)c * NPIX);
        float xs[4] = {xv.x, xv.y, xv.z, xv.w};
        float wo0 = sw[c], wo1 = sw[64 + c], ws0 = sw[128 + c], ws1 = sw[192 + c];
        #pragma unroll
        for (int i = 0; i < 4; ++i) {
            a0[i] += xs[i] * wo0;
            a1[i] += xs[i] * wo1;
            s0[i] += xs[i] * ws0;
            s1[i] += xs[i] * ws1;
        }
    }

    float v0[4], v1[4];
    #pragma unroll
    for (int i = 0; i < 4; ++i) {
        float o0 = a0[i] + bo0, o1 = a1[i] + bo1;
        float z0 = s0[i] + bs0, z1 = s1[i] + bs1;
        float g0 = 1.0f / (1.0f + __expf(-z0));
        float g1 = 1.0f / (1.0f + __expf(-z1));
        v0[i] = g0 * 0.5f * o0;
        v1[i] = g1 * 0.5f * o1;
    }

    int Hp   = p4 >> 8;        // input row
    int col  = p4 & 255;       // input col (multiple of 4)
    int hh   = Hp >> 1;
    int ipar = Hp & 1;

    // offg flat index: ((bg*HOUT + hh)*WOUT + ww)*2 + two
    //   with ww = Wp>>1, two = Wp&1  ==>  (bg*HOUT + hh)*2*WOUT + Wp  (contiguous!)
    // conv channel o -> grp = 2*o + ipar
    size_t base0 = ((size_t)((b * 4 + ipar)     * HOUT + hh)) * (2 * WOUT) + col;
    size_t base1 = ((size_t)((b * 4 + 2 + ipar) * HOUT + hh)) * (2 * WOUT) + col;
    *reinterpret_cast<float4*>(offg + base0) = make_float4(v0[0], v0[1], v0[2], v0[3]);
    *reinterpret_cast<float4*>(offg + base1) = make_float4(v1[0], v1[1], v1[2], v1[3]);
}

// -------------------------------------------------------------------------
// Kernel 2: bilinear grid-sample (align_corners=False, padding border).
// NOTE the transpose: ix (column coord) = 2*(hh+0.5+offg0)-0.5,
//                     iy (row    coord) = 2*(ww+0.5+offg1)-0.5.
// One thread per (bg, hh, ww); 16x16 output tile per block for L1/L2 reuse;
// loop over the 16 channels of the group reusing coords/weights.
// -------------------------------------------------------------------------
__global__ __launch_bounds__(256) void k_sample(
    const float* __restrict__ x,
    const float* __restrict__ offg,
    float* __restrict__ out)
{
    int blk  = blockIdx.x;
    int bg   = blk >> 6;            // 64 tiles (8x8 of 16x16) per bg
    int tile = blk & 63;
    int th   = tile >> 3, tw = tile & 7;
    int t    = threadIdx.x;
    int ww   = tw * 16 + (t & 15);
    int hh   = th * 16 + (t >> 4);
    int b    = bg >> 2, grp = bg & 3;

    size_t oidx = (((size_t)bg * HOUT + hh) * WOUT + ww) * 2;
    float off0 = offg[oidx];
    float off1 = offg[oidx + 1];

    float ix = 2.0f * ((float)hh + 0.5f + off0) - 0.5f;   // column coord (from hh!)
    float iy = 2.0f * ((float)ww + 0.5f + off1) - 0.5f;   // row coord (from ww!)
    ix = fminf(fmaxf(ix, 0.0f), (float)(WIN - 1));
    iy = fminf(fmaxf(iy, 0.0f), (float)(HIN - 1));

    float x0f = floorf(ix), y0f = floorf(iy);
    float wx = ix - x0f, wy = iy - y0f;
    int x0 = (int)x0f, y0 = (int)y0f;
    int x1 = min(x0 + 1, WIN - 1);
    int y1 = min(y0 + 1, HIN - 1);

    float w00 = (1.0f - wx) * (1.0f - wy);
    float w01 = wx * (1.0f - wy);
    float w10 = (1.0f - wx) * wy;
    float w11 = wx * wy;

    int i00 = y0 * WIN + x0, i01 = y0 * WIN + x1;
    int i10 = y1 * WIN + x0, i11 = y1 * WIN + x1;

    // input channel for loop index c is (c*4 + grp); output channel the same.
    const float* xb = x + ((size_t)b * CIN + grp) * NPIX;
    float* ob = out + (((size_t)b * CIN + grp) * HOUT + hh) * WOUT + ww;

    #pragma unroll 4
    for (int c = 0; c < 16; ++c) {
        const float* xc = xb + (size_t)c * 4 * NPIX;
        float v = xc[i00] * w00 + xc[i01] * w01 + xc[i10] * w10 + xc[i11] * w11;
        ob[(size_t)c * 4 * HOUT * WOUT] = v;
    }
}

extern "C" void kernel_launch(void* const* d_in, const int* in_sizes, int n_in,
                              void* d_out, int out_size, void* d_ws, size_t ws_size,
                              hipStream_t stream) {
    const float* x     = (const float*)d_in[0];
    const float* w_off = (const float*)d_in[1];
    const float* b_off = (const float*)d_in[2];
    const float* w_sc  = (const float*)d_in[3];
    const float* b_sc  = (const float*)d_in[4];

    float* out  = (float*)d_out;
    float* offg = out + OUT0_SIZE;   // second return value, concatenated

    // K1: BATCH * NPIX / 4 threads = 262144 -> 1024 blocks
    k_offsets<<<1024, 256, 0, stream>>>(x, w_off, b_off, w_sc, b_sc, offg);

    // K2: 64 bg * 64 tiles = 4096 blocks
    k_sample<<<4096, 256, 0, stream>>>(x, offg, out);
}

// Round 5
// 111.485 us; speedup vs baseline: 1.6719x; 1.6719x over previous
//
#include <hip/hip_runtime.h>
#include <math.h>

// Problem constants (from reference: B,C,H,W = 16,64,256,256; RATIO=2, GROUPS=4)
#define BATCH 16
#define CIN   64
#define HIN   256
#define WIN   256
#define HOUT  128
#define WOUT  128
#define NPIX  (HIN * WIN)          // 65536
#define NPIXO (HOUT * WOUT)        // 16384
#define OUT0_SIZE ((size_t)BATCH * CIN * HOUT * WOUT)   // 16777216

// -------------------------------------------------------------------------
// Kernel 1: fused conv1x1(w_off), sigmoid(conv1x1(w_sc)) * 0.5 * off,
// pixel_unshuffle + rearrange -> offg[bg, hh, ww, two]
// offg[b, grp, hh, ww, two] = off_conv[b, grp>>1, 2hh+(grp&1), 2ww+two]
// Thread handles 4 consecutive pixels (same input row) -> float4 loads/stores.
// (unchanged from round 3 — memory-bound at ~its floor)
// -------------------------------------------------------------------------
__global__ __launch_bounds__(256) void k_offsets(
    const float* __restrict__ x,
    const float* __restrict__ w_off, const float* __restrict__ b_off,
    const float* __restrict__ w_sc,  const float* __restrict__ b_sc,
    float* __restrict__ offg)
{
    __shared__ float sw[256];   // [0:64)=w_off ch0, [64:128)=w_off ch1,
                                // [128:192)=w_sc ch0, [192:256)=w_sc ch1
    int t = threadIdx.x;
    sw[t] = (t < 128) ? w_off[t] : w_sc[t - 128];
    __syncthreads();

    float bo0 = b_off[0], bo1 = b_off[1];
    float bs0 = b_sc[0],  bs1 = b_sc[1];

    int gid = blockIdx.x * 256 + t;     // total = BATCH * NPIX/4 = 262144
    int b   = gid >> 14;                // NPIX/4 = 16384 quads per batch
    int p4  = (gid & 16383) << 2;       // first of 4 consecutive pixels (same row)

    const float* xb = x + (size_t)b * CIN * NPIX + p4;

    float a0[4] = {0,0,0,0}, a1[4] = {0,0,0,0};  // off dot, ch0/ch1
    float s0[4] = {0,0,0,0}, s1[4] = {0,0,0,0};  // scale dot, ch0/ch1

    #pragma unroll 8
    for (int c = 0; c < CIN; ++c) {
        float4 xv = *reinterpret_cast<const float4*>(xb + (size_t)c * NPIX);
        float xs[4] = {xv.x, xv.y, xv.z, xv.w};
        float wo0 = sw[c], wo1 = sw[64 + c], ws0 = sw[128 + c], ws1 = sw[192 + c];
        #pragma unroll
        for (int i = 0; i < 4; ++i) {
            a0[i] += xs[i] * wo0;
            a1[i] += xs[i] * wo1;
            s0[i] += xs[i] * ws0;
            s1[i] += xs[i] * ws1;
        }
    }

    float v0[4], v1[4];
    #pragma unroll
    for (int i = 0; i < 4; ++i) {
        float o0 = a0[i] + bo0, o1 = a1[i] + bo1;
        float z0 = s0[i] + bs0, z1 = s1[i] + bs1;
        float g0 = 1.0f / (1.0f + __expf(-z0));
        float g1 = 1.0f / (1.0f + __expf(-z1));
        v0[i] = g0 * 0.5f * o0;
        v1[i] = g1 * 0.5f * o1;
    }

    int Hp   = p4 >> 8;        // input row
    int col  = p4 & 255;       // input col (multiple of 4)
    int hh   = Hp >> 1;
    int ipar = Hp & 1;

    // offg flat index collapses to (bg*HOUT + hh)*2*WOUT + Wp (contiguous)
    size_t base0 = ((size_t)((b * 4 + ipar)     * HOUT + hh)) * (2 * WOUT) + col;
    size_t base1 = ((size_t)((b * 4 + 2 + ipar) * HOUT + hh)) * (2 * WOUT) + col;
    *reinterpret_cast<float4*>(offg + base0) = make_float4(v0[0], v0[1], v0[2], v0[3]);
    *reinterpret_cast<float4*>(offg + base1) = make_float4(v1[0], v1[1], v1[2], v1[3]);
}

// -------------------------------------------------------------------------
// Kernel 2 v2: bilinear grid-sample, gather-coalesced lane mapping.
// The op transposes coordinates: ix (input COLUMN) comes from hh,
//                                iy (input ROW)    comes from ww.
// Lane mapping is hh-fast so a 16-lane segment reads one contiguous 128B
// row segment per gather (stride-2 columns + their +1 neighbors).
// Results are transposed through padded LDS so stores are coalesced.
// -------------------------------------------------------------------------
__global__ __launch_bounds__(256) void k_sample(
    const float* __restrict__ x,
    const float* __restrict__ offg,
    float* __restrict__ out)
{
    __shared__ float2 soff[16][17];    // [hh_local][ww_local], pad 17
    __shared__ float  sval[16][272];   // [ch][hh_local*17 + ww_local]

    int blk  = blockIdx.x;
    int bg   = blk >> 6;            // 64 tiles (8x8 of 16x16) per bg
    int tile = blk & 63;
    int th   = tile >> 3, tw = tile & 7;
    int t    = threadIdx.x;
    int hh0  = th * 16, ww0 = tw * 16;
    int b    = bg >> 2, grp = bg & 3;

    // ---- stage offg tile (coalesced: 16 float2 = 128B per 16-lane group) ----
    {
        int r = t >> 4, c = t & 15;    // r = hh_local, c = ww_local
        const float2* og = reinterpret_cast<const float2*>(offg)
                         + ((size_t)bg * HOUT + (hh0 + r)) * WOUT + (ww0 + c);
        soff[r][c] = *og;
    }
    __syncthreads();

    // ---- compute mapping: hh-fast within 16-lane segments ----
    int hl = t & 15;                  // hh local (fast -> drives column coord)
    int wl = t >> 4;                  // ww local (slow -> drives row coord)
    int hh = hh0 + hl;
    int ww = ww0 + wl;

    float2 off = soff[hl][wl];

    // grid math (H=W=256, h=w=128): ix = 2*(hh+0.5+off0)-0.5, iy from ww
    float ix = 2.0f * ((float)hh + 0.5f + off.x) - 0.5f;   // column coord
    float iy = 2.0f * ((float)ww + 0.5f + off.y) - 0.5f;   // row coord
    ix = fminf(fmaxf(ix, 0.0f), (float)(WIN - 1));
    iy = fminf(fmaxf(iy, 0.0f), (float)(HIN - 1));

    float x0f = floorf(ix), y0f = floorf(iy);
    float wx = ix - x0f, wy = iy - y0f;
    int x0 = (int)x0f, y0 = (int)y0f;
    int x1 = min(x0 + 1, WIN - 1);
    int y1 = min(y0 + 1, HIN - 1);

    float w00 = (1.0f - wx) * (1.0f - wy);
    float w01 = wx * (1.0f - wy);
    float w10 = (1.0f - wx) * wy;
    float w11 = wx * wy;

    int i00 = y0 * WIN + x0;
    int i10 = y1 * WIN + x0;
    int i01 = y0 * WIN + x1;
    int i11 = y1 * WIN + x1;

    const float* xb = x + ((size_t)b * CIN + grp) * NPIX;

    float v[16];
    // fast path: x0 even with a real right neighbor -> aligned float2 loads
    // (uniformly true for this data: offsets ~1e-2 -> x0 = 2*hh)
    bool fastp = ((x0 & 1) == 0) && (x1 == x0 + 1);
    if (fastp) {
        #pragma unroll
        for (int c = 0; c < 16; ++c) {
            const float* xc = xb + (size_t)c * 4 * NPIX;
            float2 a  = *reinterpret_cast<const float2*>(xc + i00);
            float2 d  = *reinterpret_cast<const float2*>(xc + i10);
            v[c] = a.x * w00 + a.y * w01 + d.x * w10 + d.y * w11;
        }
    } else {
        #pragma unroll
        for (int c = 0; c < 16; ++c) {
            const float* xc = xb + (size_t)c * 4 * NPIX;
            v[c] = xc[i00] * w00 + xc[i01] * w01 + xc[i10] * w10 + xc[i11] * w11;
        }
    }

    // ---- transpose through LDS (pitch 17: conflict-free both directions) ----
    #pragma unroll
    for (int c = 0; c < 16; ++c)
        sval[c][hl * 17 + wl] = v[c];
    __syncthreads();

    // ---- coalesced store: thread t -> (hh = hh0 + t>>4, ww = ww0 + t&15) ----
    int sh = t >> 4, sc = t & 15;
    float* ob = out + (((size_t)b * CIN + grp) * HOUT + (hh0 + sh)) * WOUT
              + (ww0 + sc);
    #pragma unroll
    for (int c = 0; c < 16; ++c)
        ob[(size_t)c * 4 * NPIXO] = sval[c][sh * 17 + sc];
}

extern "C" void kernel_launch(void* const* d_in, const int* in_sizes, int n_in,
                              void* d_out, int out_size, void* d_ws, size_t ws_size,
                              hipStream_t stream) {
    const float* x     = (const float*)d_in[0];
    const float* w_off = (const float*)d_in[1];
    const float* b_off = (const float*)d_in[2];
    const float* w_sc  = (const float*)d_in[3];
    const float* b_sc  = (const float*)d_in[4];

    float* out  = (float*)d_out;
    float* offg = out + OUT0_SIZE;   // second return value, concatenated

    // K1: BATCH * NPIX / 4 threads = 262144 -> 1024 blocks
    k_offsets<<<1024, 256, 0, stream>>>(x, w_off, b_off, w_sc, b_sc, offg);

    // K2: 64 bg * 64 tiles = 4096 blocks
    k_sample<<<4096, 256, 0, stream>>>(x, offg, out);
}

// Round 6
// 102.334 us; speedup vs baseline: 1.8214x; 1.0894x over previous
//
#include <hip/hip_runtime.h>
#include <math.h>

// Problem constants (B,C,H,W = 16,64,256,256; RATIO=2, GROUPS=4)
#define BATCH 16
#define CIN   64
#define HIN   256
#define WIN   256
#define HOUT  128
#define WOUT  128
#define NPIX  (HIN * WIN)          // 65536
#define NPIXO (HOUT * WOUT)        // 16384
#define OUT0_SIZE ((size_t)BATCH * CIN * HOUT * WOUT)   // 16777216

// ---------------------------------------------------------------------------
// Fully fused kernel. One block = one (b, 16x16 output tile), 256 threads.
//
// Phase 1 (conv / offsets): thread t owns output pixel (row=t>>4, col=t&15)
//   and its 2x2 conv-pixel block at input rows {2hh,2hh+1} cols {2ww,2ww+1}.
//   Per channel: two float2 loads (16 consecutive lanes = 128B contiguous),
//   16 FMAs into 16 accumulators. Each input pixel is read exactly once
//   chip-wide. offg[grp][two] = sig(s_o)*0.5*(a_o) at conv pixel
//   (i=grp&1, j=two), o=grp>>1 — all 8 values are thread-local.
//   Written coalesced to global (float2) and into LDS soff for phase 2.
//
// Phase 2 (grid sample): remap thread to hh-fast (hl=t&15 drives the input
//   COLUMN coord, wl=t>>4 drives the ROW coord — the op transposes coords).
//   Gather region of tile (p,q) ~= conv region of partner tile (q,p), which
//   is <=63 blocks away in dispatch order -> L3-resident. 4 scalar gathers
//   per channel; results transposed through padded LDS for coalesced stores.
//
// LDS ~78KB -> 2 blocks/CU, keeping the chip-wide phase1->phase2 reuse
// footprint (~512 blocks * 0.26MB = 133MB) inside the 256MB L3.
// ---------------------------------------------------------------------------
__global__ __launch_bounds__(256) void k_fused(
    const float* __restrict__ x,
    const float* __restrict__ w_off, const float* __restrict__ b_off,
    const float* __restrict__ w_sc,  const float* __restrict__ b_sc,
    float* __restrict__ out, float* __restrict__ offg)
{
    __shared__ float  sw[256];            // w_off ch0/ch1, w_sc ch0/ch1
    __shared__ float2 soff[4][16][17];    // [grp][row][col], padded
    __shared__ float  sval[4][16][272];   // [grp][c][hl*17+wl], padded

    int t = threadIdx.x;
    sw[t] = (t < 128) ? w_off[t] : w_sc[t - 128];

    int blk  = blockIdx.x;
    int b    = blk >> 6;
    int tile = blk & 63;
    int hh0  = (tile >> 3) * 16;   // p
    int ww0  = (tile & 7) * 16;    // q  (partner (q,p) is <=63 blocks away)

    // ---------------- phase 1: conv1x1 offsets ----------------
    int row = t >> 4, col = t & 15;       // ww-fast mapping
    int hh = hh0 + row, ww = ww0 + col;

    const float* xb = x + (size_t)b * CIN * NPIX + (2 * hh) * WIN + 2 * ww;

    float aA0[2][2] = {{0,0},{0,0}}, aA1[2][2] = {{0,0},{0,0}};
    float aS0[2][2] = {{0,0},{0,0}}, aS1[2][2] = {{0,0},{0,0}};

    __syncthreads();   // sw ready

    #pragma unroll 8
    for (int c = 0; c < CIN; ++c) {
        const float* xc = xb + (size_t)c * NPIX;
        float2 r0 = *reinterpret_cast<const float2*>(xc);        // row 2hh
        float2 r1 = *reinterpret_cast<const float2*>(xc + WIN);  // row 2hh+1
        float wo0 = sw[c], wo1 = sw[64 + c], ws0 = sw[128 + c], ws1 = sw[192 + c];
        aA0[0][0] += r0.x * wo0;  aA0[0][1] += r0.y * wo0;
        aA0[1][0] += r1.x * wo0;  aA0[1][1] += r1.y * wo0;
        aA1[0][0] += r0.x * wo1;  aA1[0][1] += r0.y * wo1;
        aA1[1][0] += r1.x * wo1;  aA1[1][1] += r1.y * wo1;
        aS0[0][0] += r0.x * ws0;  aS0[0][1] += r0.y * ws0;
        aS0[1][0] += r1.x * ws0;  aS0[1][1] += r1.y * ws0;
        aS1[0][0] += r0.x * ws1;  aS1[0][1] += r0.y * ws1;
        aS1[1][0] += r1.x * ws1;  aS1[1][1] += r1.y * ws1;
    }

    float bo0 = b_off[0], bo1 = b_off[1];
    float bs0 = b_sc[0],  bs1 = b_sc[1];

    // offg[grp][two]: grp = 2*o + i (i = conv row parity), two = j (col parity)
    float og[4][2];
    #pragma unroll
    for (int i = 0; i < 2; ++i) {
        #pragma unroll
        for (int j = 0; j < 2; ++j) {
            float g0 = 1.0f / (1.0f + __expf(-(aS0[i][j] + bs0)));
            float g1 = 1.0f / (1.0f + __expf(-(aS1[i][j] + bs1)));
            og[i][j]     = g0 * 0.5f * (aA0[i][j] + bo0);
            og[2 + i][j] = g1 * 0.5f * (aA1[i][j] + bo1);
        }
    }

    #pragma unroll
    for (int g = 0; g < 4; ++g) {
        float2 vv = make_float2(og[g][0], og[g][1]);
        soff[g][row][col] = vv;
        size_t oi = ((size_t)((b * 4 + g) * HOUT + hh)) * WOUT + ww;
        *reinterpret_cast<float2*>(offg + 2 * oi) = vv;   // coalesced float2
    }
    __syncthreads();

    // ---------------- phase 2: bilinear grid sample ----------------
    int hl = t & 15, wl = t >> 4;          // hh-fast: gather coalescing
    int shh = hh0 + hl, sww = ww0 + wl;
    const float* xg = x + (size_t)b * CIN * NPIX;

    #pragma unroll
    for (int g = 0; g < 4; ++g) {
        float2 off = soff[g][hl][wl];
        // transposed coords: ix (column) from hh, iy (row) from ww
        float ix = 2.0f * ((float)shh + 0.5f + off.x) - 0.5f;
        float iy = 2.0f * ((float)sww + 0.5f + off.y) - 0.5f;
        ix = fminf(fmaxf(ix, 0.0f), (float)(WIN - 1));
        iy = fminf(fmaxf(iy, 0.0f), (float)(HIN - 1));

        float x0f = floorf(ix), y0f = floorf(iy);
        float wx = ix - x0f, wy = iy - y0f;
        int x0 = (int)x0f, y0 = (int)y0f;
        int x1 = min(x0 + 1, WIN - 1);
        int y1 = min(y0 + 1, HIN - 1);

        float w00 = (1.0f - wx) * (1.0f - wy);
        float w01 = wx * (1.0f - wy);
        float w10 = (1.0f - wx) * wy;
        float w11 = wx * wy;

        int i00 = y0 * WIN + x0, i01 = y0 * WIN + x1;
        int i10 = y1 * WIN + x0, i11 = y1 * WIN + x1;

        const float* xgc = xg + (size_t)g * NPIX;   // channel c*4+g
        #pragma unroll 4
        for (int c = 0; c < 16; ++c) {
            const float* xc = xgc + (size_t)c * 4 * NPIX;
            float v = xc[i00] * w00 + xc[i01] * w01
                    + xc[i10] * w10 + xc[i11] * w11;
            sval[g][c][hl * 17 + wl] = v;
        }
    }
    __syncthreads();

    // coalesced stores (transposed back via padded LDS)
    int sh = t >> 4, sc = t & 15;
    float* ob = out + (((size_t)b * CIN) * HOUT + (hh0 + sh)) * WOUT + (ww0 + sc);
    #pragma unroll
    for (int g = 0; g < 4; ++g) {
        #pragma unroll 4
        for (int c = 0; c < 16; ++c)
            ob[(size_t)(c * 4 + g) * NPIXO] = sval[g][c][sh * 17 + sc];
    }
}

extern "C" void kernel_launch(void* const* d_in, const int* in_sizes, int n_in,
                              void* d_out, int out_size, void* d_ws, size_t ws_size,
                              hipStream_t stream) {
    const float* x     = (const float*)d_in[0];
    const float* w_off = (const float*)d_in[1];
    const float* b_off = (const float*)d_in[2];
    const float* w_sc  = (const float*)d_in[3];
    const float* b_sc  = (const float*)d_in[4];

    float* out  = (float*)d_out;
    float* offg = out + OUT0_SIZE;   // second return value, concatenated

    // 16 batches x 64 tiles = 1024 blocks of 256 threads
    k_fused<<<1024, 256, 0, stream>>>(x, w_off, b_off, w_sc, b_sc, out, offg);
}

// Round 7
// 97.702 us; speedup vs baseline: 1.9078x; 1.0474x over previous
//
#include <hip/hip_runtime.h>
#include <math.h>

// Problem constants (B,C,H,W = 16,64,256,256; RATIO=2, GROUPS=4)
#define BATCH 16
#define CIN   64
#define HIN   256
#define WIN   256
#define HOUT  128
#define WOUT  128
#define NPIX  (HIN * WIN)          // 65536
#define NPIXO (HOUT * WOUT)        // 16384
#define OUT0_SIZE ((size_t)BATCH * CIN * HOUT * WOUT)   // 16777216

// ---------------------------------------------------------------------------
// Fully fused kernel, v2 (occupancy-oriented).
//
// Phase 1 (conv/offsets): unchanged from round 6 — thread owns a 2x2 input
//   block; each input pixel read exactly once chip-wide; offg thread-local.
//
// Phase 2 (grid sample): groups processed SEQUENTIALLY through a single
//   sval[16][272] transpose buffer -> LDS drops 77.5KB -> ~27KB, so the
//   whole 1024-block grid is co-resident (4 blocks/CU, 16 waves/CU) for
//   latency hiding of the L3-hit gathers. float2 fast-path gather halves
//   VMEM instructions. out/offg use nontemporal stores so the 83MB of
//   writes don't evict x from the 256MB L3 (phase-2 hit-rate protection).
// ---------------------------------------------------------------------------
__global__ __launch_bounds__(256) void k_fused(
    const float* __restrict__ x,
    const float* __restrict__ w_off, const float* __restrict__ b_off,
    const float* __restrict__ w_sc,  const float* __restrict__ b_sc,
    float* __restrict__ out, float* __restrict__ offg)
{
    __shared__ float  sw[256];            // w_off ch0/ch1, w_sc ch0/ch1
    __shared__ float2 soff[4][16][17];    // [grp][row][col], padded
    __shared__ float  sval[16][272];      // [c][hl*17+wl], one group at a time

    int t = threadIdx.x;
    sw[t] = (t < 128) ? w_off[t] : w_sc[t - 128];

    int blk  = blockIdx.x;
    int b    = blk >> 6;
    int tile = blk & 63;
    int hh0  = (tile >> 3) * 16;   // p
    int ww0  = (tile & 7) * 16;    // q  (partner (q,p) is <=63 blocks away)

    // ---------------- phase 1: conv1x1 offsets ----------------
    int row = t >> 4, col = t & 15;       // ww-fast mapping
    int hh = hh0 + row, ww = ww0 + col;

    const float* xb = x + (size_t)b * CIN * NPIX + (2 * hh) * WIN + 2 * ww;

    float aA0[2][2] = {{0,0},{0,0}}, aA1[2][2] = {{0,0},{0,0}};
    float aS0[2][2] = {{0,0},{0,0}}, aS1[2][2] = {{0,0},{0,0}};

    __syncthreads();   // sw ready

    #pragma unroll 8
    for (int c = 0; c < CIN; ++c) {
        const float* xc = xb + (size_t)c * NPIX;
        float2 r0 = *reinterpret_cast<const float2*>(xc);        // row 2hh
        float2 r1 = *reinterpret_cast<const float2*>(xc + WIN);  // row 2hh+1
        float wo0 = sw[c], wo1 = sw[64 + c], ws0 = sw[128 + c], ws1 = sw[192 + c];
        aA0[0][0] += r0.x * wo0;  aA0[0][1] += r0.y * wo0;
        aA0[1][0] += r1.x * wo0;  aA0[1][1] += r1.y * wo0;
        aA1[0][0] += r0.x * wo1;  aA1[0][1] += r0.y * wo1;
        aA1[1][0] += r1.x * wo1;  aA1[1][1] += r1.y * wo1;
        aS0[0][0] += r0.x * ws0;  aS0[0][1] += r0.y * ws0;
        aS0[1][0] += r1.x * ws0;  aS0[1][1] += r1.y * ws0;
        aS1[0][0] += r0.x * ws1;  aS1[0][1] += r0.y * ws1;
        aS1[1][0] += r1.x * ws1;  aS1[1][1] += r1.y * ws1;
    }

    float bo0 = b_off[0], bo1 = b_off[1];
    float bs0 = b_sc[0],  bs1 = b_sc[1];

    // offg[grp][two]: grp = 2*o + i (conv row parity), two = j (col parity)
    float og[4][2];
    #pragma unroll
    for (int i = 0; i < 2; ++i) {
        #pragma unroll
        for (int j = 0; j < 2; ++j) {
            float g0 = 1.0f / (1.0f + __expf(-(aS0[i][j] + bs0)));
            float g1 = 1.0f / (1.0f + __expf(-(aS1[i][j] + bs1)));
            og[i][j]     = g0 * 0.5f * (aA0[i][j] + bo0);
            og[2 + i][j] = g1 * 0.5f * (aA1[i][j] + bo1);
        }
    }

    #pragma unroll
    for (int g = 0; g < 4; ++g) {
        float2 vv = make_float2(og[g][0], og[g][1]);
        soff[g][row][col] = vv;
        size_t oi = ((size_t)((b * 4 + g) * HOUT + hh)) * WOUT + ww;
        // nontemporal 8B store: offg is write-only output, keep it out of L3
        __builtin_nontemporal_store(__builtin_bit_cast(double, vv),
                                    reinterpret_cast<double*>(offg + 2 * oi));
    }
    __syncthreads();

    // ---------------- phase 2: bilinear grid sample, group-sequential ------
    int hl = t & 15, wl = t >> 4;          // hh-fast: gather coalescing
    int shh = hh0 + hl, sww = ww0 + wl;
    const float* xg = x + (size_t)b * CIN * NPIX;

    int sh = t >> 4, sc = t & 15;          // store mapping (ww-fast)
    float* ob = out + (((size_t)b * CIN) * HOUT + (hh0 + sh)) * WOUT + (ww0 + sc);

    for (int g = 0; g < 4; ++g) {
        float2 off = soff[g][hl][wl];
        // transposed coords: ix (column) from hh, iy (row) from ww
        float ix = 2.0f * ((float)shh + 0.5f + off.x) - 0.5f;
        float iy = 2.0f * ((float)sww + 0.5f + off.y) - 0.5f;
        ix = fminf(fmaxf(ix, 0.0f), (float)(WIN - 1));
        iy = fminf(fmaxf(iy, 0.0f), (float)(HIN - 1));

        float x0f = floorf(ix), y0f = floorf(iy);
        float wx = ix - x0f, wy = iy - y0f;
        int x0 = (int)x0f, y0 = (int)y0f;
        int x1 = min(x0 + 1, WIN - 1);
        int y1 = min(y0 + 1, HIN - 1);

        float w00 = (1.0f - wx) * (1.0f - wy);
        float w01 = wx * (1.0f - wy);
        float w10 = (1.0f - wx) * wy;
        float w11 = wx * wy;

        int i00 = y0 * WIN + x0, i01 = y0 * WIN + x1;
        int i10 = y1 * WIN + x0, i11 = y1 * WIN + x1;

        const float* xgc = xg + (size_t)g * NPIX;   // channel c*4+g

        float v[16];
        // fast path: x0 even with real right neighbor -> aligned float2 loads
        // (uniformly true for this data: offsets ~1e-2 -> x0 = 2*hh)
        bool fastp = ((x0 & 1) == 0) && (x1 == x0 + 1);
        if (fastp) {
            #pragma unroll
            for (int c = 0; c < 16; ++c) {
                const float* xc = xgc + (size_t)c * 4 * NPIX;
                float2 a = *reinterpret_cast<const float2*>(xc + i00);
                float2 d = *reinterpret_cast<const float2*>(xc + i10);
                v[c] = a.x * w00 + a.y * w01 + d.x * w10 + d.y * w11;
            }
        } else {
            #pragma unroll
            for (int c = 0; c < 16; ++c) {
                const float* xc = xgc + (size_t)c * 4 * NPIX;
                v[c] = xc[i00] * w00 + xc[i01] * w01
                     + xc[i10] * w10 + xc[i11] * w11;
            }
        }

        __syncthreads();   // previous group's sval reads complete
        #pragma unroll
        for (int c = 0; c < 16; ++c)
            sval[c][hl * 17 + wl] = v[c];
        __syncthreads();   // sval ready

        // coalesced nontemporal stores (don't evict x from L3)
        #pragma unroll
        for (int c = 0; c < 16; ++c)
            __builtin_nontemporal_store(sval[c][sh * 17 + sc],
                                        &ob[(size_t)(c * 4 + g) * NPIXO]);
    }
}

extern "C" void kernel_launch(void* const* d_in, const int* in_sizes, int n_in,
                              void* d_out, int out_size, void* d_ws, size_t ws_size,
                              hipStream_t stream) {
    const float* x     = (const float*)d_in[0];
    const float* w_off = (const float*)d_in[1];
    const float* b_off = (const float*)d_in[2];
    const float* w_sc  = (const float*)d_in[3];
    const float* b_sc  = (const float*)d_in[4];

    float* out  = (float*)d_out;
    float* offg = out + OUT0_SIZE;   // second return value, concatenated

    // 16 batches x 64 tiles = 1024 blocks of 256 threads (whole grid resident)
    k_fused<<<1024, 256, 0, stream>>>(x, w_off, b_off, w_sc, b_sc, out, offg);
}